// Round 14
// baseline (191.783 us; speedup 1.0000x reference)
//
#include <hip/hip_runtime.h>
#include <math.h>
#include <limits.h>

// B=524288, D_IN=128, H=16, D_OUT=4. Round 14 = Round 11 core (104.7us champ)
// made PERSISTENT: grid=1024 (exactly 4 blocks/CU, ONE generation), 2 tiles
// per block, cross-tile pipeline: h(t+1) reg-loads at kc=7, x0(t+1) staged
// right after gates, x1(t+1) at loop entry -> loads stay in flight through
// the compute-only tail. Transpose buffer = B with 16-word XOR-swizzled rows
// (bank-uniform, frees A for the x0 prefetch). vmcnt accounting includes
// stores (they increment vmcnt). All value-producing arithmetic bitwise-
// identical to rounds 1-13 (absmax 0.0 every round).

// ---- d_ws layout (4-byte words) ----
#define OFF_QS    0
#define OFF_SFC1  4
#define OFF_SG    20
#define OFF_QG    84
#define OFF_SCF   148
#define OFF_SCIG  164
#define OFF_SOD   180
#define OFF_SXO   196
#define OFF_VBG   200
#define OFF_TI    216
#define OFF_TF    280
#define OFF_TO    344
#define OFF_TG    408
#define OFF_IGT   536
#define OFF_ODT   1064
#define OFF_W1P   1192
#define OFF_WIHP  1704
#define OFF_WHHP  1960
#define OFF_WOUTP 2216

__device__ __forceinline__ float qclip(float v) {
    return fminf(fmaxf(v, -127.0f), 127.0f);
}

__device__ __forceinline__ int sdot4(int a, int b, int c) {
#if __has_builtin(__builtin_amdgcn_sdot4)
    return __builtin_amdgcn_sdot4(a, b, c, false);
#else
    c += ((a << 24) >> 24) * ((b << 24) >> 24);
    c += ((a << 16) >> 24) * ((b << 16) >> 24);
    c += ((a << 8)  >> 24) * ((b << 8)  >> 24);
    c += (a >> 24) * (b >> 24);
    return c;
#endif
}

__device__ __forceinline__ int pack4i(int a, int b, int c, int d) {
    return (a & 255) | ((b & 255) << 8) | ((c & 255) << 16) | (d << 24);
}

__device__ __forceinline__ int pack4f(const float* p) {
    return pack4i((int)p[0], (int)p[1], (int)p[2], (int)p[3]);
}

typedef __attribute__((address_space(1))) const void g_void;
typedef __attribute__((address_space(3))) void l_void;

__device__ __forceinline__ void stage16(const float* g, float* l) {
    __builtin_amdgcn_global_load_lds((g_void*)g, (l_void*)l, 16, 0, 0);
}

#define WAIT_VM0()   { asm volatile("s_waitcnt vmcnt(0)" ::: "memory"); __builtin_amdgcn_sched_barrier(0); }
#define WAIT_VM4()   { asm volatile("s_waitcnt vmcnt(4)" ::: "memory"); __builtin_amdgcn_sched_barrier(0); }
#define WAIT_LGKM0() { asm volatile("s_waitcnt lgkmcnt(0)" ::: "memory"); __builtin_amdgcn_sched_barrier(0); }

// exact reference chains (bitwise = validated rounds)
__device__ __forceinline__ int qeval_sig(int gi, float s, float q) {
    float v = (float)gi / s;
    float a = 1.0f / (1.0f + expf(-v));
    return (int)qclip(rintf(a * q));
}
__device__ __forceinline__ int qeval_tanh(int gi, float s, float q) {
    float v = (float)gi / s;
    float a = tanhf(v);
    return (int)qclip(rintf(a * q));
}

#define GLIM 1048576

__device__ int search_thr_sig(float s, float q, int target) {
    if (qeval_sig(GLIM, s, q) < target) return INT_MAX;
    int lo = -GLIM, hi = GLIM;
    while (hi - lo > 1) {
        int mid = lo + ((hi - lo) >> 1);
        if (qeval_sig(mid, s, q) >= target) hi = mid; else lo = mid;
    }
    return hi;
}
__device__ int search_thr_tanh(float s, float q, int target) {
    if (qeval_tanh(GLIM, s, q) < target) return INT_MAX;
    int lo = -GLIM, hi = GLIM;
    while (hi - lo > 1) {
        int mid = lo + ((hi - lo) >> 1);
        if (qeval_tanh(mid, s, q) >= target) hi = mid; else lo = mid;
    }
    return hi;
}

// One fused setup kernel (no inter-thread memory deps).
__global__ void __launch_bounds__(1024) setup_all(
    const float* __restrict__ w1, const float* __restrict__ w_ih,
    const float* __restrict__ w_hh, const float* __restrict__ w_out,
    const float* __restrict__ a_in0, const float* __restrict__ a_w0,
    const float* __restrict__ a_lstm, const float* __restrict__ a_wl,
    const float* __restrict__ a_out, const float* __restrict__ a_wo,
    float* __restrict__ wsf)
{
    const int t = threadIdx.x;
    int* wsi = (int*)wsf;
    const float amax_in0 = a_in0[0], amax_lstm = a_lstm[0], amax_out = a_out[0];

    if (t == 0) {
        wsf[OFF_QS + 0] = 127.0f / amax_in0;
        wsf[OFF_QS + 1] = 127.0f / amax_lstm;
        wsf[OFF_QS + 2] = 127.0f / amax_out;
    }
    if (t < 16) wsf[OFF_SFC1 + t] = 16129.0f / (amax_in0 * a_w0[t]);
    if (t < 64) {
        float am = amax_lstm * a_wl[t];
        wsf[OFF_SG + t] = 16129.0f / am;
        wsf[OFF_QG + t] = 127.0f / am;
    }
    if (t < 16) {
        float amf = amax_lstm * a_wl[16 + t];
        wsf[OFF_SCF + t] = 16129.0f / (amf * 3.4764f);
        float amo = amax_lstm * a_wl[48 + t];
        wsf[OFF_SOD + t] = 127.0f / amo;
        float ami = amax_lstm * a_wl[t];
        float amg = amax_lstm * a_wl[32 + t];
        wsf[OFF_SCIG + t] = 16129.0f / (ami * amg);
        float s = 16129.0f / amg, q = 127.0f / amg;
        wsi[OFF_VBG + t] = qeval_tanh(-GLIM, s, q);
    }
    if (t < 4) wsf[OFF_SXO + t] = 16129.0f / (amax_out * a_wo[t]);

    if (t < 512) wsi[OFF_W1P + t] = pack4f(w1 + 4 * t);
    if (t < 256) { wsi[OFF_WIHP + t] = pack4f(w_ih + 4 * t);
                   wsi[OFF_WHHP + t] = pack4f(w_hh + 4 * t); }
    if (t < 16)  wsi[OFF_WOUTP + t] = pack4f(w_out + 4 * t);

    if (t < 64) {
        int m = t >> 2, k = t & 3;
        float am = amax_lstm * a_wl[m];
        wsi[OFF_TI + t] = search_thr_sig(16129.0f / am, 127.0f / am, k + 1);
    } else if (t < 128) {
        int u = t - 64, m = u >> 2, k = u & 3;
        float am = amax_lstm * a_wl[16 + m];
        wsi[OFF_TF + u] = search_thr_sig(16129.0f / am, 127.0f / am, k + 1);
    } else if (t < 192) {
        int u = t - 128, m = u >> 2, k = u & 3;
        float am = amax_lstm * a_wl[48 + m];
        wsi[OFF_TO + u] = search_thr_sig(16129.0f / am, 127.0f / am, k + 1);
    } else if (t < 320) {
        int u = t - 192, m = u >> 3, k = u & 7;
        float am = amax_lstm * a_wl[32 + m];
        float s = 16129.0f / am, q = 127.0f / am;
        int vb = qeval_tanh(-GLIM, s, q);
        wsi[OFF_TG + u] = search_thr_tanh(s, q, vb + 1 + k);
    } else if (t < 848) {
        int u = t - 320, m = u / 33, p = u % 33;
        float ami = amax_lstm * a_wl[m];
        float amg = amax_lstm * a_wl[32 + m];
        float scig = 16129.0f / (ami * amg);
        wsf[OFF_IGT + u] = (float)(p - 16) / scig;
    } else if (t < 928) {
        int u = t - 848, m = u / 5, oq = u % 5;
        float amo = amax_lstm * a_wl[48 + m];
        float sod = 127.0f / amo;
        wsf[OFF_ODT + m * 8 + oq] = (float)oq / sod;
    }
}

#define NBLK 1024
#define TILES 2

__global__ void __launch_bounds__(256, 4) mlpq_kernel(
    const float* __restrict__ x, const float* __restrict__ h, const float* __restrict__ c,
    const float* __restrict__ wsf,
    float* __restrict__ out_xo, float* __restrict__ out_hy, float* __restrict__ out_cy,
    int nrows)
{
    __shared__ float s_tab[656];                        // igt 528 + odt 128
    __shared__ __align__(1024) float s_stage[4][2048];  // A(1024) + B(1024) per wave

    for (int i = threadIdx.x; i < 656; i += 256) s_tab[i] = wsf[OFF_IGT + i];
    __syncthreads();
    const float* s_igt = s_tab;
    const float* s_odt = s_tab + 528;

    const int tid = threadIdx.x;
    const int wv  = tid >> 6;
    const int rl  = tid & 63;
    const int sw = (rl >> 1) & 3;                       // read-side slot swizzle
    const int qs_stage = (rl & 3) ^ ((rl >> 3) & 3);    // quarter this lane stages
    const int g2 = rl >> 2;                             // transpose read row-sub
    const int mq = rl & 3;

    float* A = &s_stage[wv][0];
    float* B = &s_stage[wv][1024];

    const int* __restrict__ wsi = (const int*)wsf;
    const float qs_in   = wsf[OFF_QS + 0];
    const float qs_lstm = wsf[OFF_QS + 1];
    const float qs_out  = wsf[OFF_QS + 2];

    // ---------- prologue (tile 0): h -> regs, x0 -> A
    float4 hv4[4];
    {
        const int r0 = blockIdx.x * 256 + wv * 64 + rl;
        const float4* hb = reinterpret_cast<const float4*>(h) + (size_t)r0 * 4;
#pragma unroll
        for (int jg = 0; jg < 4; ++jg) hv4[jg] = hb[jg];
        const int rs0 = blockIdx.x * 256 + wv * 64 + (rl >> 2);
        const float* g0 = x + (size_t)rs0 * 128 + qs_stage * 4;
        stage16(g0 + 0 * 2048, A + 0 * 256);
        stage16(g0 + 1 * 2048, A + 1 * 256);
        stage16(g0 + 2 * 2048, A + 2 * 256);
        stage16(g0 + 3 * 2048, A + 3 * 256);
    }

#pragma unroll 1
    for (int t = 0; t < TILES; ++t) {
        const int wrow0 = (blockIdx.x + t * NBLK) * 256 + wv * 64;
        const int r = wrow0 + rl;
        const int rstage = wrow0 + (rl >> 2);
        const float* gpx = x + (size_t)rstage * 128 + qs_stage * 4;
        const float* gpc = c + (size_t)rstage * 16 + qs_stage * 4;

        // entry: stage x1 -> B (WAR vs prev tile's transpose reads)
        WAIT_LGKM0();
        {
            const float* g = gpx + 16;
            stage16(g + 0 * 2048, B + 0 * 256);
            stage16(g + 1 * 2048, B + 1 * 256);
            stage16(g + 2 * 2048, B + 2 * 256);
            stage16(g + 3 * 2048, B + 3 * 256);
        }

        int acc[16];
#pragma unroll
        for (int j = 0; j < 16; ++j) acc[j] = 0;
        int hql[4];
        float4 hv4n[4];

        // ---------- fc1: 8 chunks, depth-2 counted-vmcnt (even->A, odd->B)
#pragma unroll
        for (int kc = 0; kc < 8; ++kc) {
            WAIT_VM4();                 // chunk kc resident (4 newest = kc+1 etc.)
            float* bk = (kc & 1) ? B : A;
            const float4* b4 = reinterpret_cast<const float4*>(bk);
            float4 xv[4];
#pragma unroll
            for (int q = 0; q < 4; ++q) xv[q] = b4[rl * 4 + (q ^ sw)];
            WAIT_LGKM0();               // reads retired -> buffer reusable
            if (kc <= 5) {
                const float* g = gpx + (kc + 2) * 16;
                stage16(g + 0 * 2048, bk + 0 * 256);
                stage16(g + 1 * 2048, bk + 1 * 256);
                stage16(g + 2 * 2048, bk + 2 * 256);
                stage16(g + 3 * 2048, bk + 3 * 256);
            } else if (kc == 6) {       // c -> A
                stage16(gpc + 0 * 256, bk + 0 * 256);
                stage16(gpc + 1 * 256, bk + 1 * 256);
                stage16(gpc + 2 * 256, bk + 2 * 256);
                stage16(gpc + 3 * 256, bk + 3 * 256);
            } else {                    // kc == 7: next tile's h -> regs
                if (t < TILES - 1) {
                    const int rn = (blockIdx.x + (t + 1) * NBLK) * 256 + wv * 64 + rl;
                    const float4* hb = reinterpret_cast<const float4*>(h) + (size_t)rn * 4;
#pragma unroll
                    for (int jg = 0; jg < 4; ++jg) hv4n[jg] = hb[jg];
                }
            }
            if (kc == 0) {              // h(t) retired by this point (VM4 above)
#pragma unroll
                for (int jg = 0; jg < 4; ++jg) {
                    float4 v = hv4[jg];
                    hql[jg] = pack4i((int)qclip(rintf(v.x * qs_lstm)),
                                     (int)qclip(rintf(v.y * qs_lstm)),
                                     (int)qclip(rintf(v.z * qs_lstm)),
                                     (int)qclip(rintf(v.w * qs_lstm)));
                }
            }
#pragma unroll
            for (int q = 0; q < 4; ++q) {
                float4 v = xv[q];
                int w = pack4i((int)qclip(rintf(v.x * qs_in)),
                               (int)qclip(rintf(v.y * qs_in)),
                               (int)qclip(rintf(v.z * qs_in)),
                               (int)qclip(rintf(v.w * qs_in)));
#pragma unroll
                for (int j = 0; j < 16; ++j)
                    acc[j] = sdot4(w, wsi[OFF_W1P + j * 32 + kc * 4 + q], acc[j]);
            }
        }

        // ---------- relu + dequant(double) + requant (overlaps c staging)
        int aql[4];
#pragma unroll
        for (int jg = 0; jg < 4; ++jg) {
            int q[4];
#pragma unroll
            for (int u = 0; u < 4; ++u) {
                int j = jg * 4 + u;
                int ai = acc[j] > 0 ? acc[j] : 0;
                float dq = (float)ai / wsf[OFF_SFC1 + j];
                q[u] = (int)qclip(rintf(dq * qs_lstm));
            }
            aql[jg] = pack4i(q[0], q[1], q[2], q[3]);
        }

        if (t < TILES - 1) { WAIT_VM4(); }  // c retired (h_next outstanding)
        else               { WAIT_VM0(); }  // last tile: only c outstanding

        // ---------- MLSTM cell; c from A, hy/cy in regs
        const float4* c4 = reinterpret_cast<const float4*>(A);
        float hyv[16], cyv[16];
        int xql[4];

#pragma unroll
        for (int mg = 0; mg < 4; ++mg) {
            float4 cv = c4[rl * 4 + (mg ^ sw)];
            float cvals[4] = {cv.x, cv.y, cv.z, cv.w};
            int xq4[4];
#pragma unroll
            for (int tt = 0; tt < 4; ++tt) {
                const int m = mg * 4 + tt;
                int gi = 0, gf = 0, gg = 0, go = 0;
#pragma unroll
                for (int p = 0; p < 4; ++p) {
                    int ap = aql[p], hp = hql[p];
                    gi = sdot4(ap, wsi[OFF_WIHP + (m)      * 4 + p], gi);
                    gi = sdot4(hp, wsi[OFF_WHHP + (m)      * 4 + p], gi);
                    gf = sdot4(ap, wsi[OFF_WIHP + (m + 16) * 4 + p], gf);
                    gf = sdot4(hp, wsi[OFF_WHHP + (m + 16) * 4 + p], gf);
                    gg = sdot4(ap, wsi[OFF_WIHP + (m + 32) * 4 + p], gg);
                    gg = sdot4(hp, wsi[OFF_WHHP + (m + 32) * 4 + p], gg);
                    go = sdot4(ap, wsi[OFF_WIHP + (m + 48) * 4 + p], go);
                    go = sdot4(hp, wsi[OFF_WHHP + (m + 48) * 4 + p], go);
                }
                int iq = (gi >= wsi[OFF_TI + m * 4 + 0]) + (gi >= wsi[OFF_TI + m * 4 + 1])
                       + (gi >= wsi[OFF_TI + m * 4 + 2]) + (gi >= wsi[OFF_TI + m * 4 + 3]);
                int fq = (gf >= wsi[OFF_TF + m * 4 + 0]) + (gf >= wsi[OFF_TF + m * 4 + 1])
                       + (gf >= wsi[OFF_TF + m * 4 + 2]) + (gf >= wsi[OFF_TF + m * 4 + 3]);
                int oq = (go >= wsi[OFF_TO + m * 4 + 0]) + (go >= wsi[OFF_TO + m * 4 + 1])
                       + (go >= wsi[OFF_TO + m * 4 + 2]) + (go >= wsi[OFF_TO + m * 4 + 3]);
                int gq = wsi[OFF_VBG + m]
                       + (gg >= wsi[OFF_TG + m * 8 + 0]) + (gg >= wsi[OFF_TG + m * 8 + 1])
                       + (gg >= wsi[OFF_TG + m * 8 + 2]) + (gg >= wsi[OFF_TG + m * 8 + 3])
                       + (gg >= wsi[OFF_TG + m * 8 + 4]) + (gg >= wsi[OFF_TG + m * 8 + 5])
                       + (gg >= wsi[OFF_TG + m * 8 + 6]) + (gg >= wsi[OFF_TG + m * 8 + 7]);

                int cqv = (int)qclip(rintf(cvals[tt] * qs_lstm));

                float cy = (float)(fq * cqv) / wsf[OFF_SCF + m]
                         + s_igt[m * 33 + (iq * gq + 16)];
                float od = s_odt[m * 8 + oq];
                float hy = od * tanhf(cy);

                hyv[m] = hy;
                cyv[m] = cy;
                xq4[tt] = (int)qclip(rintf(hy * qs_out));
            }
            xql[mg] = pack4i(xq4[0], xq4[1], xq4[2], xq4[3]);
        }

        // ---------- prefetch next tile's x0 -> A (c reads done)
        WAIT_LGKM0();
        if (t < TILES - 1) {
            const int rsn = (blockIdx.x + (t + 1) * NBLK) * 256 + wv * 64 + (rl >> 2);
            const float* gn = x + (size_t)rsn * 128 + qs_stage * 4;
            stage16(gn + 0 * 2048, A + 0 * 256);
            stage16(gn + 1 * 2048, A + 1 * 256);
            stage16(gn + 2 * 2048, A + 2 * 256);
            stage16(gn + 3 * 2048, A + 3 * 256);
        }

        // ---------- output layer (int8 dot4, exact)
        float4 xov;
        {
            int s0 = 0, s1 = 0, s2 = 0, s3 = 0;
#pragma unroll
            for (int p = 0; p < 4; ++p) {
                s0 = sdot4(xql[p], wsi[OFF_WOUTP + 0 * 4 + p], s0);
                s1 = sdot4(xql[p], wsi[OFF_WOUTP + 1 * 4 + p], s1);
                s2 = sdot4(xql[p], wsi[OFF_WOUTP + 2 * 4 + p], s2);
                s3 = sdot4(xql[p], wsi[OFF_WOUTP + 3 * 4 + p], s3);
            }
            xov.x = (float)s0 / wsf[OFF_SXO + 0];
            xov.y = (float)s1 / wsf[OFF_SXO + 1];
            xov.z = (float)s2 / wsf[OFF_SXO + 2];
            xov.w = (float)s3 / wsf[OFF_SXO + 3];
        }
        reinterpret_cast<float4*>(out_xo)[r] = xov;   // dense (16B/row)

        // ---------- DENSE hy/cy stores via B, 16-word XOR-swizzled rows ----
        // slot(row, q) = q ^ ((row>>1)&3): bank-uniform on write AND read.
        float4* hb4 = reinterpret_cast<float4*>(out_hy) + (size_t)wrow0 * 4;
        float4* cb4 = reinterpret_cast<float4*>(out_cy) + (size_t)wrow0 * 4;
        const int wsl = (rl >> 1) & 3;                // write swizzle key
#pragma unroll
        for (int q = 0; q < 4; ++q)
            *reinterpret_cast<float4*>(&B[rl * 16 + ((q ^ wsl) << 2)]) =
                make_float4(hyv[q * 4 + 0], hyv[q * 4 + 1], hyv[q * 4 + 2], hyv[q * 4 + 3]);
        WAIT_LGKM0();
#pragma unroll
        for (int s = 0; s < 4; ++s) {
            const int R = s * 16 + g2;
            float4 v = *reinterpret_cast<const float4*>(&B[R * 16 + ((mq ^ ((R >> 1) & 3)) << 2)]);
            hb4[s * 64 + rl] = v;
        }
        WAIT_LGKM0();
#pragma unroll
        for (int q = 0; q < 4; ++q)
            *reinterpret_cast<float4*>(&B[rl * 16 + ((q ^ wsl) << 2)]) =
                make_float4(cyv[q * 4 + 0], cyv[q * 4 + 1], cyv[q * 4 + 2], cyv[q * 4 + 3]);
        WAIT_LGKM0();
#pragma unroll
        for (int s = 0; s < 4; ++s) {
            const int R = s * 16 + g2;
            float4 v = *reinterpret_cast<const float4*>(&B[R * 16 + ((mq ^ ((R >> 1) & 3)) << 2)]);
            cb4[s * 64 + rl] = v;
        }

        // carry next tile's h
        if (t < TILES - 1) {
#pragma unroll
            for (int jg = 0; jg < 4; ++jg) hv4[jg] = hv4n[jg];
        }
    }
}

extern "C" void kernel_launch(void* const* d_in, const int* in_sizes, int n_in,
                              void* d_out, int out_size, void* d_ws, size_t ws_size,
                              hipStream_t stream) {
    const float* x      = (const float*)d_in[0];
    const float* h      = (const float*)d_in[1];
    const float* c      = (const float*)d_in[2];
    const float* w1     = (const float*)d_in[3];
    const float* w_ih   = (const float*)d_in[4];
    const float* w_hh   = (const float*)d_in[5];
    const float* w_out  = (const float*)d_in[6];
    const float* a_in0  = (const float*)d_in[7];
    const float* a_w0   = (const float*)d_in[8];
    const float* a_lstm = (const float*)d_in[9];
    const float* a_wl   = (const float*)d_in[10];
    const float* a_out  = (const float*)d_in[11];
    const float* a_wo   = (const float*)d_in[12];

    const int B = in_sizes[0] / 128;  // 524288 = 1024 * 2 * 256
    float* out    = (float*)d_out;
    float* out_xo = out;
    float* out_hy = out + (size_t)B * 4;
    float* out_cy = out + (size_t)B * 20;
    float* wsf    = (float*)d_ws;

    hipLaunchKernelGGL(setup_all, dim3(1), dim3(1024), 0, stream,
                       w1, w_ih, w_hh, w_out, a_in0, a_w0, a_lstm, a_wl, a_out, a_wo, wsf);

    dim3 block(256);
    dim3 grid(NBLK);   // 1024 = 4 blocks/CU, one resident generation
    hipLaunchKernelGGL(mlpq_kernel, grid, block, 0, stream,
                       x, h, c, wsf, out_xo, out_hy, out_cy, B);
}

// Round 16
// 100.415 us; speedup vs baseline: 1.9099x; 1.9099x over previous
//
#include <hip/hip_runtime.h>
#include <math.h>
#include <limits.h>

// B=524288, D_IN=128, H=16, D_OUT=4. Round 16 = Round 11 (104.7us champion:
// depth-2 counted-vmcnt LDS x-staging, staged h/c, dense transposed hy/cy
// stores) + ONE change: all output stores are NONTEMPORAL (xo, hy, cy).
// (R15 retry: nontemporal builtin needs a native vector type, not HIP's
// float4 class -> use ext_vector_type(4) float alias for the store.)
// Outputs are write-once/never-read; nt stores reduce L2/L3 pollution so the
// caches retain more of x. Values bit-identical (cache policy only).
// All value-producing arithmetic bitwise-identical to rounds 1-14.

// ---- d_ws layout (4-byte words) ----
#define OFF_QS    0
#define OFF_SFC1  4
#define OFF_SG    20
#define OFF_QG    84
#define OFF_SCF   148
#define OFF_SCIG  164
#define OFF_SOD   180
#define OFF_SXO   196
#define OFF_VBG   200
#define OFF_TI    216
#define OFF_TF    280
#define OFF_TO    344
#define OFF_TG    408
#define OFF_IGT   536
#define OFF_ODT   1064
#define OFF_W1P   1192
#define OFF_WIHP  1704
#define OFF_WHHP  1960
#define OFF_WOUTP 2216

typedef float nfloat4 __attribute__((ext_vector_type(4)));

__device__ __forceinline__ float qclip(float v) {
    return fminf(fmaxf(v, -127.0f), 127.0f);
}

__device__ __forceinline__ int sdot4(int a, int b, int c) {
#if __has_builtin(__builtin_amdgcn_sdot4)
    return __builtin_amdgcn_sdot4(a, b, c, false);
#else
    c += ((a << 24) >> 24) * ((b << 24) >> 24);
    c += ((a << 16) >> 24) * ((b << 16) >> 24);
    c += ((a << 8)  >> 24) * ((b << 8)  >> 24);
    c += (a >> 24) * (b >> 24);
    return c;
#endif
}

__device__ __forceinline__ int pack4i(int a, int b, int c, int d) {
    return (a & 255) | ((b & 255) << 8) | ((c & 255) << 16) | (d << 24);
}

__device__ __forceinline__ int pack4f(const float* p) {
    return pack4i((int)p[0], (int)p[1], (int)p[2], (int)p[3]);
}

__device__ __forceinline__ void nt_store4(float4* p, float4 v) {
    nfloat4 nv;
    nv.x = v.x; nv.y = v.y; nv.z = v.z; nv.w = v.w;
    __builtin_nontemporal_store(nv, reinterpret_cast<nfloat4*>(p));
}

typedef __attribute__((address_space(1))) const void g_void;
typedef __attribute__((address_space(3))) void l_void;

__device__ __forceinline__ void stage16(const float* g, float* l) {
    __builtin_amdgcn_global_load_lds((g_void*)g, (l_void*)l, 16, 0, 0);
}

#define WAIT_VM0()   { asm volatile("s_waitcnt vmcnt(0)" ::: "memory"); __builtin_amdgcn_sched_barrier(0); }
#define WAIT_VM4()   { asm volatile("s_waitcnt vmcnt(4)" ::: "memory"); __builtin_amdgcn_sched_barrier(0); }
#define WAIT_LGKM0() { asm volatile("s_waitcnt lgkmcnt(0)" ::: "memory"); __builtin_amdgcn_sched_barrier(0); }

// exact reference chains (bitwise = validated rounds)
__device__ __forceinline__ int qeval_sig(int gi, float s, float q) {
    float v = (float)gi / s;
    float a = 1.0f / (1.0f + expf(-v));
    return (int)qclip(rintf(a * q));
}
__device__ __forceinline__ int qeval_tanh(int gi, float s, float q) {
    float v = (float)gi / s;
    float a = tanhf(v);
    return (int)qclip(rintf(a * q));
}

#define GLIM 1048576

__device__ int search_thr_sig(float s, float q, int target) {
    if (qeval_sig(GLIM, s, q) < target) return INT_MAX;
    int lo = -GLIM, hi = GLIM;
    while (hi - lo > 1) {
        int mid = lo + ((hi - lo) >> 1);
        if (qeval_sig(mid, s, q) >= target) hi = mid; else lo = mid;
    }
    return hi;
}
__device__ int search_thr_tanh(float s, float q, int target) {
    if (qeval_tanh(GLIM, s, q) < target) return INT_MAX;
    int lo = -GLIM, hi = GLIM;
    while (hi - lo > 1) {
        int mid = lo + ((hi - lo) >> 1);
        if (qeval_tanh(mid, s, q) >= target) hi = mid; else lo = mid;
    }
    return hi;
}

// One fused setup kernel (no inter-thread memory deps).
__global__ void __launch_bounds__(1024) setup_all(
    const float* __restrict__ w1, const float* __restrict__ w_ih,
    const float* __restrict__ w_hh, const float* __restrict__ w_out,
    const float* __restrict__ a_in0, const float* __restrict__ a_w0,
    const float* __restrict__ a_lstm, const float* __restrict__ a_wl,
    const float* __restrict__ a_out, const float* __restrict__ a_wo,
    float* __restrict__ wsf)
{
    const int t = threadIdx.x;
    int* wsi = (int*)wsf;
    const float amax_in0 = a_in0[0], amax_lstm = a_lstm[0], amax_out = a_out[0];

    if (t == 0) {
        wsf[OFF_QS + 0] = 127.0f / amax_in0;
        wsf[OFF_QS + 1] = 127.0f / amax_lstm;
        wsf[OFF_QS + 2] = 127.0f / amax_out;
    }
    if (t < 16) wsf[OFF_SFC1 + t] = 16129.0f / (amax_in0 * a_w0[t]);
    if (t < 64) {
        float am = amax_lstm * a_wl[t];
        wsf[OFF_SG + t] = 16129.0f / am;
        wsf[OFF_QG + t] = 127.0f / am;
    }
    if (t < 16) {
        float amf = amax_lstm * a_wl[16 + t];
        wsf[OFF_SCF + t] = 16129.0f / (amf * 3.4764f);
        float amo = amax_lstm * a_wl[48 + t];
        wsf[OFF_SOD + t] = 127.0f / amo;
        float ami = amax_lstm * a_wl[t];
        float amg = amax_lstm * a_wl[32 + t];
        wsf[OFF_SCIG + t] = 16129.0f / (ami * amg);
        float s = 16129.0f / amg, q = 127.0f / amg;
        wsi[OFF_VBG + t] = qeval_tanh(-GLIM, s, q);
    }
    if (t < 4) wsf[OFF_SXO + t] = 16129.0f / (amax_out * a_wo[t]);

    if (t < 512) wsi[OFF_W1P + t] = pack4f(w1 + 4 * t);
    if (t < 256) { wsi[OFF_WIHP + t] = pack4f(w_ih + 4 * t);
                   wsi[OFF_WHHP + t] = pack4f(w_hh + 4 * t); }
    if (t < 16)  wsi[OFF_WOUTP + t] = pack4f(w_out + 4 * t);

    if (t < 64) {
        int m = t >> 2, k = t & 3;
        float am = amax_lstm * a_wl[m];
        wsi[OFF_TI + t] = search_thr_sig(16129.0f / am, 127.0f / am, k + 1);
    } else if (t < 128) {
        int u = t - 64, m = u >> 2, k = u & 3;
        float am = amax_lstm * a_wl[16 + m];
        wsi[OFF_TF + u] = search_thr_sig(16129.0f / am, 127.0f / am, k + 1);
    } else if (t < 192) {
        int u = t - 128, m = u >> 2, k = u & 3;
        float am = amax_lstm * a_wl[48 + m];
        wsi[OFF_TO + u] = search_thr_sig(16129.0f / am, 127.0f / am, k + 1);
    } else if (t < 320) {
        int u = t - 192, m = u >> 3, k = u & 7;
        float am = amax_lstm * a_wl[32 + m];
        float s = 16129.0f / am, q = 127.0f / am;
        int vb = qeval_tanh(-GLIM, s, q);
        wsi[OFF_TG + u] = search_thr_tanh(s, q, vb + 1 + k);
    } else if (t < 848) {
        int u = t - 320, m = u / 33, p = u % 33;
        float ami = amax_lstm * a_wl[m];
        float amg = amax_lstm * a_wl[32 + m];
        float scig = 16129.0f / (ami * amg);
        wsf[OFF_IGT + u] = (float)(p - 16) / scig;
    } else if (t < 928) {
        int u = t - 848, m = u / 5, oq = u % 5;
        float amo = amax_lstm * a_wl[48 + m];
        float sod = 127.0f / amo;
        wsf[OFF_ODT + m * 8 + oq] = (float)oq / sod;
    }
}

__global__ void __launch_bounds__(256) mlpq_kernel(
    const float* __restrict__ x, const float* __restrict__ h, const float* __restrict__ c,
    const float* __restrict__ wsf,
    float* __restrict__ out_xo, float* __restrict__ out_hy, float* __restrict__ out_cy,
    int nrows)
{
    __shared__ float s_tab[656];                        // igt 528 + odt 128
    __shared__ __align__(1024) float s_stage[4][2048];  // 2 x 4KB per wave

    for (int i = threadIdx.x; i < 656; i += 256) s_tab[i] = wsf[OFF_IGT + i];
    __syncthreads();
    const float* s_igt = s_tab;
    const float* s_odt = s_tab + 528;

    const int tid = threadIdx.x;
    const int wv  = tid >> 6;
    const int rl  = tid & 63;
    const int wrow0 = blockIdx.x * 256 + wv * 64;
    const int r = wrow0 + rl;

    const int sw = (rl >> 1) & 3;                       // read-side slot swizzle
    const int qs_stage = (rl & 3) ^ ((rl >> 3) & 3);    // quarter this lane stages
    const int rstage = wrow0 + (rl >> 2);               // row this lane stages

    float* bufE = &s_stage[wv][0];        // h in bufO; x0,x2,x4,x6,c in bufE
    float* bufO = &s_stage[wv][1024];     // x1,x3,x5,x7 in bufO

    const int* __restrict__ wsi = (const int*)wsf;
    const float qs_in   = wsf[OFF_QS + 0];
    const float qs_lstm = wsf[OFF_QS + 1];
    const float qs_out  = wsf[OFF_QS + 2];

    const float* gph = h + (size_t)rstage * 16 + qs_stage * 4;
    const float* gpc = c + (size_t)rstage * 16 + qs_stage * 4;
    const float* gpx = x + (size_t)rstage * 128 + qs_stage * 4;

    // ---------- prologue: co-issue h -> bufO and x chunk0 -> bufE
    stage16(gph + 0 * 256, bufO + 0 * 256);
    stage16(gph + 1 * 256, bufO + 1 * 256);
    stage16(gph + 2 * 256, bufO + 2 * 256);
    stage16(gph + 3 * 256, bufO + 3 * 256);
    stage16(gpx + 0 * 2048, bufE + 0 * 256);
    stage16(gpx + 1 * 2048, bufE + 1 * 256);
    stage16(gpx + 2 * 2048, bufE + 2 * 256);
    stage16(gpx + 3 * 2048, bufE + 3 * 256);

    WAIT_VM4();   // h retired; x0 in flight
    float4 hv[4];
    {
        const float4* b4 = reinterpret_cast<const float4*>(bufO);
#pragma unroll
        for (int q = 0; q < 4; ++q) hv[q] = b4[rl * 4 + (q ^ sw)];
    }
    WAIT_LGKM0();
    {   // bufO free: stage x chunk1 (depth-2 established)
        const float* g = gpx + 1 * 16;
        stage16(g + 0 * 2048, bufO + 0 * 256);
        stage16(g + 1 * 2048, bufO + 1 * 256);
        stage16(g + 2 * 2048, bufO + 2 * 256);
        stage16(g + 3 * 2048, bufO + 3 * 256);
    }
    int hql[4];
#pragma unroll
    for (int q = 0; q < 4; ++q) {
        float4 v = hv[q];
        hql[q] = pack4i((int)qclip(rintf(v.x * qs_lstm)),
                        (int)qclip(rintf(v.y * qs_lstm)),
                        (int)qclip(rintf(v.z * qs_lstm)),
                        (int)qclip(rintf(v.w * qs_lstm)));
    }

    // ---------- fc1 over 8 chunks, depth-2 counted-vmcnt pipeline
    int acc[16];
#pragma unroll
    for (int j = 0; j < 16; ++j) acc[j] = 0;

#pragma unroll
    for (int kc = 0; kc < 8; ++kc) {
        WAIT_VM4();   // chunk kc retired; next still in flight
        float* bk = (kc & 1) ? bufO : bufE;
        const float4* b4 = reinterpret_cast<const float4*>(bk);
        float4 xv[4];
#pragma unroll
        for (int q = 0; q < 4; ++q) xv[q] = b4[rl * 4 + (q ^ sw)];
        WAIT_LGKM0();
        if (kc <= 5) {
            const float* g = gpx + (kc + 2) * 16;
            stage16(g + 0 * 2048, bk + 0 * 256);
            stage16(g + 1 * 2048, bk + 1 * 256);
            stage16(g + 2 * 2048, bk + 2 * 256);
            stage16(g + 3 * 2048, bk + 3 * 256);
        } else if (kc == 6) {
            stage16(gpc + 0 * 256, bk + 0 * 256);
            stage16(gpc + 1 * 256, bk + 1 * 256);
            stage16(gpc + 2 * 256, bk + 2 * 256);
            stage16(gpc + 3 * 256, bk + 3 * 256);
        }
#pragma unroll
        for (int q = 0; q < 4; ++q) {
            float4 v = xv[q];
            int w = pack4i((int)qclip(rintf(v.x * qs_in)),
                           (int)qclip(rintf(v.y * qs_in)),
                           (int)qclip(rintf(v.z * qs_in)),
                           (int)qclip(rintf(v.w * qs_in)));
#pragma unroll
            for (int j = 0; j < 16; ++j)
                acc[j] = sdot4(w, wsi[OFF_W1P + j * 32 + kc * 4 + q], acc[j]);
        }
    }

    // ---------- relu + dequant(double) + requant (overlaps c staging)
    int aql[4];
#pragma unroll
    for (int jg = 0; jg < 4; ++jg) {
        int q[4];
#pragma unroll
        for (int u = 0; u < 4; ++u) {
            int j = jg * 4 + u;
            int ai = acc[j] > 0 ? acc[j] : 0;
            float dq = (float)ai / wsf[OFF_SFC1 + j];
            q[u] = (int)qclip(rintf(dq * qs_lstm));
        }
        aql[jg] = pack4i(q[0], q[1], q[2], q[3]);
    }

    WAIT_VM0();  // c staged (in bufE)

    // ---------- MLSTM cell; hy/cy kept in registers
    const float4* c4 = reinterpret_cast<const float4*>(bufE);
    float hyv[16], cyv[16];
    int xql[4];

#pragma unroll
    for (int mg = 0; mg < 4; ++mg) {
        float4 cv = c4[rl * 4 + (mg ^ sw)];
        float cvals[4] = {cv.x, cv.y, cv.z, cv.w};
        int xq4[4];
#pragma unroll
        for (int t = 0; t < 4; ++t) {
            const int m = mg * 4 + t;
            int gi = 0, gf = 0, gg = 0, go = 0;
#pragma unroll
            for (int p = 0; p < 4; ++p) {
                int ap = aql[p], hp = hql[p];
                gi = sdot4(ap, wsi[OFF_WIHP + (m)      * 4 + p], gi);
                gi = sdot4(hp, wsi[OFF_WHHP + (m)      * 4 + p], gi);
                gf = sdot4(ap, wsi[OFF_WIHP + (m + 16) * 4 + p], gf);
                gf = sdot4(hp, wsi[OFF_WHHP + (m + 16) * 4 + p], gf);
                gg = sdot4(ap, wsi[OFF_WIHP + (m + 32) * 4 + p], gg);
                gg = sdot4(hp, wsi[OFF_WHHP + (m + 32) * 4 + p], gg);
                go = sdot4(ap, wsi[OFF_WIHP + (m + 48) * 4 + p], go);
                go = sdot4(hp, wsi[OFF_WHHP + (m + 48) * 4 + p], go);
            }
            int iq = (gi >= wsi[OFF_TI + m * 4 + 0]) + (gi >= wsi[OFF_TI + m * 4 + 1])
                   + (gi >= wsi[OFF_TI + m * 4 + 2]) + (gi >= wsi[OFF_TI + m * 4 + 3]);
            int fq = (gf >= wsi[OFF_TF + m * 4 + 0]) + (gf >= wsi[OFF_TF + m * 4 + 1])
                   + (gf >= wsi[OFF_TF + m * 4 + 2]) + (gf >= wsi[OFF_TF + m * 4 + 3]);
            int oq = (go >= wsi[OFF_TO + m * 4 + 0]) + (go >= wsi[OFF_TO + m * 4 + 1])
                   + (go >= wsi[OFF_TO + m * 4 + 2]) + (go >= wsi[OFF_TO + m * 4 + 3]);
            int gq = wsi[OFF_VBG + m]
                   + (gg >= wsi[OFF_TG + m * 8 + 0]) + (gg >= wsi[OFF_TG + m * 8 + 1])
                   + (gg >= wsi[OFF_TG + m * 8 + 2]) + (gg >= wsi[OFF_TG + m * 8 + 3])
                   + (gg >= wsi[OFF_TG + m * 8 + 4]) + (gg >= wsi[OFF_TG + m * 8 + 5])
                   + (gg >= wsi[OFF_TG + m * 8 + 6]) + (gg >= wsi[OFF_TG + m * 8 + 7]);

            int cqv = (int)qclip(rintf(cvals[t] * qs_lstm));

            float cy = (float)(fq * cqv) / wsf[OFF_SCF + m]
                     + s_igt[m * 33 + (iq * gq + 16)];
            float od = s_odt[m * 8 + oq];
            float hy = od * tanhf(cy);

            hyv[m] = hy;
            cyv[m] = cy;
            xq4[t] = (int)qclip(rintf(hy * qs_out));
        }
        xql[mg] = pack4i(xq4[0], xq4[1], xq4[2], xq4[3]);
    }

    // ---------- output layer (int8 dot4, exact)
    float4 xov;
    {
        int s0 = 0, s1 = 0, s2 = 0, s3 = 0;
#pragma unroll
        for (int p = 0; p < 4; ++p) {
            s0 = sdot4(xql[p], wsi[OFF_WOUTP + 0 * 4 + p], s0);
            s1 = sdot4(xql[p], wsi[OFF_WOUTP + 1 * 4 + p], s1);
            s2 = sdot4(xql[p], wsi[OFF_WOUTP + 2 * 4 + p], s2);
            s3 = sdot4(xql[p], wsi[OFF_WOUTP + 3 * 4 + p], s3);
        }
        xov.x = (float)s0 / wsf[OFF_SXO + 0];
        xov.y = (float)s1 / wsf[OFF_SXO + 1];
        xov.z = (float)s2 / wsf[OFF_SXO + 2];
        xov.w = (float)s3 / wsf[OFF_SXO + 3];
    }
    nt_store4(reinterpret_cast<float4*>(out_xo) + r, xov);   // dense, nontemporal

    // ---------- DENSE hy/cy stores via wave-private LDS transpose ----------
    // 20-word padded rows (80B, b128-aligned every row); stage bufs dead.
    float* tb = &s_stage[wv][0];                  // 2048 words >= 64*20
    const int g  = (rl >> 2);
    const int mq = rl & 3;
    float4* hb4 = reinterpret_cast<float4*>(out_hy) + (size_t)wrow0 * 4;
    float4* cb4 = reinterpret_cast<float4*>(out_cy) + (size_t)wrow0 * 4;

    WAIT_LGKM0();   // c b128 reads retired (WAR on s_stage)
#pragma unroll
    for (int q = 0; q < 4; ++q)
        *reinterpret_cast<float4*>(&tb[rl * 20 + q * 4]) =
            make_float4(hyv[q * 4 + 0], hyv[q * 4 + 1], hyv[q * 4 + 2], hyv[q * 4 + 3]);
    WAIT_LGKM0();
#pragma unroll
    for (int s = 0; s < 4; ++s) {
        float4 v = *reinterpret_cast<const float4*>(&tb[(s * 16 + g) * 20 + mq * 4]);
        nt_store4(hb4 + s * 64 + rl, v);          // 64 lanes x 16B contiguous, nt
    }
    WAIT_LGKM0();
#pragma unroll
    for (int q = 0; q < 4; ++q)
        *reinterpret_cast<float4*>(&tb[rl * 20 + q * 4]) =
            make_float4(cyv[q * 4 + 0], cyv[q * 4 + 1], cyv[q * 4 + 2], cyv[q * 4 + 3]);
    WAIT_LGKM0();
#pragma unroll
    for (int s = 0; s < 4; ++s) {
        float4 v = *reinterpret_cast<const float4*>(&tb[(s * 16 + g) * 20 + mq * 4]);
        nt_store4(cb4 + s * 64 + rl, v);
    }
}

extern "C" void kernel_launch(void* const* d_in, const int* in_sizes, int n_in,
                              void* d_out, int out_size, void* d_ws, size_t ws_size,
                              hipStream_t stream) {
    const float* x      = (const float*)d_in[0];
    const float* h      = (const float*)d_in[1];
    const float* c      = (const float*)d_in[2];
    const float* w1     = (const float*)d_in[3];
    const float* w_ih   = (const float*)d_in[4];
    const float* w_hh   = (const float*)d_in[5];
    const float* w_out  = (const float*)d_in[6];
    const float* a_in0  = (const float*)d_in[7];
    const float* a_w0   = (const float*)d_in[8];
    const float* a_lstm = (const float*)d_in[9];
    const float* a_wl   = (const float*)d_in[10];
    const float* a_out  = (const float*)d_in[11];
    const float* a_wo   = (const float*)d_in[12];

    const int B = in_sizes[0] / 128;  // 524288 (multiple of 256)
    float* out    = (float*)d_out;
    float* out_xo = out;
    float* out_hy = out + (size_t)B * 4;
    float* out_cy = out + (size_t)B * 20;
    float* wsf    = (float*)d_ws;

    hipLaunchKernelGGL(setup_all, dim3(1), dim3(1024), 0, stream,
                       w1, w_ih, w_hh, w_out, a_in0, a_w0, a_lstm, a_wl, a_out, a_wo, wsf);

    dim3 block(256);
    dim3 grid((B + 255) / 256);
    hipLaunchKernelGGL(mlpq_kernel, grid, block, 0, stream,
                       x, h, c, wsf, out_xo, out_hy, out_cy, B);
}